// Round 4
// baseline (292.563 us; speedup 1.0000x reference)
//
#include <hip/hip_runtime.h>

// KAN conv feature extractor, fully fused: one workgroup (256 thr) per TWO batch
// elements.  conv1 3x3 (1->5) + maxpool2 -> conv2 5x5 (5->5) -> conv3 3x3 (5->2)
// -> FC(98->200).
// Activations in LDS as fp16 "records" of 12 halves (24B): [silu, B0..B7, 0, p, p].
// Inner products via v_dot2_f32_f16 (fp32 accumulate).  Conv weights pre-packed to
// fp16 10-half records in d_ws (wave-uniform indices -> s_load).  FC weights packed
// as pair-transposed fp16.  B-spline basis evaluated analytically (4 cubics/span).

typedef _Float16 h2 __attribute__((ext_vector_type(2)));
typedef unsigned int uint_t;

__device__ __forceinline__ h2 as_h2(uint_t u) { union { uint_t u; h2 h; } c; c.u = u; return c.h; }
__device__ __forceinline__ uint_t pk(float a, float b) {
    h2 v; v[0] = (_Float16)a; v[1] = (_Float16)b;
    union { h2 h; uint_t u; } c; c.h = v; return c.u;
}
__device__ __forceinline__ float fdot2f(h2 a, h2 b, float c) {
#if __has_builtin(__builtin_amdgcn_fdot2)
    return __builtin_amdgcn_fdot2(a, b, c, false);
#else
    return c + (float)a[0] * (float)b[0] + (float)a[1] * (float)b[1];
#endif
}

__device__ __forceinline__ float silu_f(float v) {
    return v / (1.0f + __expf(-v));
}

// Analytic cubic B-spline over uniform knots g_i = 0.4*i - 2.2 (i = 0..11).
// For x in span s (g_s <= x < g_s+1), t = local coord: nonzero bases are
// j = s-3..s with the 4 standard cubics.  Continuous across knots, so fp32
// span-rounding at boundaries is harmless.  Outside [-2.2, 2.2): all zero.
// Writes fp16 record [silu, B0..B7, 0, 0, 0] (12 halves, 8B-aligned).
__device__ __forceinline__ void write_rec(_Float16* p, float v) {
    float u  = (v + 2.2f) * 2.5f;
    float fs = floorf(u);
    float t  = u - fs;
    float t2 = t * t, t3 = t2 * t;
    const float c6 = 1.0f / 6.0f;
    float q3 = t3 * c6;                                   // b[s]
    float q2 = (-3.f * t3 + 3.f * t2 + 3.f * t + 1.f) * c6; // b[s-1]
    float q1 = (3.f * t3 - 6.f * t2 + 4.f) * c6;          // b[s-2]
    float omt = 1.f - t;
    float q0 = omt * omt * omt * c6;                      // b[s-3]
    int si = (int)fs;
    bool valid = (u >= 0.0f) && (u < 11.0f);
    si = valid ? si : 1000;
    float bs[8];
#pragma unroll
    for (int j = 0; j < 8; ++j) {
        int d = si - j;
        bs[j] = (d == 0) ? q3 : (d == 1) ? q2 : (d == 2) ? q1 : (d == 3) ? q0 : 0.0f;
    }
    float sl = silu_f(v);
    uint2 w0, w1;
    w0.x = pk(sl, bs[0]);    w0.y = pk(bs[1], bs[2]);
    w1.x = pk(bs[3], bs[4]); w1.y = pk(bs[5], bs[6]);
    *(uint2*)(p)      = w0;
    *(uint2*)(p + 4)  = w1;
    *(uint_t*)(p + 8) = pk(bs[7], 0.0f);
}

struct Rec { h2 a[5]; };
__device__ __forceinline__ Rec load_rec(const _Float16* p) {
    uint2  u0 = *(const uint2*)(p);
    uint2  u1 = *(const uint2*)(p + 4);
    uint_t u2 = *(const uint_t*)(p + 8);
    Rec r;
    r.a[0] = as_h2(u0.x); r.a[1] = as_h2(u0.y);
    r.a[2] = as_h2(u1.x); r.a[3] = as_h2(u1.y);
    r.a[4] = as_h2(u2);
    return r;
}

// d_ws layout:
//   [0)       w16: fp16 conv weight records, 10 halves each:
//               W1 rec (c*9+t)            : 45 recs  @ half 0
//               W2 rec (o*125+c*25+di*5+dj): 625 recs @ half 450
//               W3 rec (o*45+c*9+di*3+dj) : 90 recs  @ half 6700
//   [15360)   fcw16: uint [49][200], pair (fcw[o][2j], fcw[o][2j+1]) as h2
#define W2_OFF 450
#define W3_OFF 6700
#define FCW16_BYTE_OFF 15360

__global__ __launch_bounds__(256) void kan_prep(
    const float* __restrict__ wb1, const float* __restrict__ ws1,
    const float* __restrict__ wb2, const float* __restrict__ ws2,
    const float* __restrict__ wb3, const float* __restrict__ ws3,
    const float* __restrict__ fcw, _Float16* __restrict__ w16,
    uint_t* __restrict__ fcw16)
{
    int gtid = blockIdx.x * 256 + threadIdx.x;
    int gstr = gridDim.x * 256;
    for (int i = gtid; i < 760; i += gstr) {
        const float *wb, *ws; int r;
        if (i < 45)       { wb = wb1; ws = ws1; r = i; }
        else if (i < 670) { wb = wb2; ws = ws2; r = i - 45; }
        else              { wb = wb3; ws = ws3; r = i - 670; }
        _Float16* p = w16 + i * 10;
        p[0] = (_Float16)wb[r];
#pragma unroll
        for (int g = 0; g < 8; ++g) p[1 + g] = (_Float16)ws[r * 8 + g];
        p[9] = (_Float16)0.0f;
    }
    for (int i = gtid; i < 9800; i += gstr) {
        int j2 = i / 200, o = i % 200;
        fcw16[j2 * 200 + o] = pk(fcw[o * 98 + 2 * j2], fcw[o * 98 + 2 * j2 + 1]);
    }
}

// LDS per sample: smemA (10140 halves, overlaid): t1 [784][12] | t2 [169][5][12]
//   | t3 [81][5][12].  smemB (3380 halves, overlaid): P2h fp16 [5][676] |
//   h2buf f32 [405] | h3 fp16 [98].
// 2 samples: total 54,080 B -> 3 WGs/CU (12 waves) at 128 VGPRs.
#define SREC 10140
#define SB   3380

__global__ __launch_bounds__(256, 4) void kan_fused(
    const float* __restrict__ x,      // [B,1,28,28]
    const _Float16* __restrict__ w16, // packed conv weights (d_ws)
    const uint_t* __restrict__ fcw16, // [49][200] h2 pairs
    const float* __restrict__ fcb,    // [200]
    float* __restrict__ out,          // [B,200]
    int B)
{
    __shared__ __align__(16) _Float16 smemA[2 * SREC];
    __shared__ __align__(16) _Float16 smemB[2 * SB];

    const int b0  = blockIdx.x * 2;
    const int tid = threadIdx.x;

    // ---- Phase 1: transform input pixels -> t1 records (both samples) ----
#pragma unroll 1
    for (int i = tid; i < 1568; i += 256) {
        int s = (i >= 784);
        int pix = i - (s ? 784 : 0);
        float v = (b0 + s < B) ? x[(b0 + s) * 784 + pix] : 0.0f;
        write_rec(&smemA[s * SREC + pix * 12], v);
    }
    __syncthreads();

    // ---- Phase 2: conv1 3x3 at every sub-position (26x26), 5 out ch ------
#pragma unroll 1
    for (int i = tid; i < 1352; i += 256) {
        int s = (i >= 676);
        int sub = i - (s ? 676 : 0);
        const _Float16* sm = smemA + s * SREC;
        _Float16* P2h = smemB + s * SB;
        int y = sub / 26, xx = sub % 26;
        Rec r[9];
#pragma unroll
        for (int t = 0; t < 9; ++t)
            r[t] = load_rec(&sm[((y + t / 3) * 28 + xx + t % 3) * 12]);
        float acc[5] = {0.f, 0.f, 0.f, 0.f, 0.f};
#pragma unroll
        for (int t = 0; t < 9; ++t) {
#pragma unroll
            for (int c = 0; c < 5; ++c) {
                const h2* w = (const h2*)(w16 + (c * 9 + t) * 10);
                float a = acc[c];
#pragma unroll
                for (int q = 0; q < 5; ++q) a = fdot2f(r[t].a[q], w[q], a);
                acc[c] = a;
            }
        }
#pragma unroll
        for (int c = 0; c < 5; ++c) P2h[c * 676 + sub] = (_Float16)acc[c];
    }
    __syncthreads();

    // ---- Phase 3: maxpool2 + transform -> t2 records ---------------------
#pragma unroll 1
    for (int i = tid; i < 1690; i += 256) {
        int s = (i >= 845);
        int r2 = i - (s ? 845 : 0);
        int c = r2 / 169, pp = r2 % 169;
        const _Float16* P2h = smemB + s * SB;
        int ph = pp / 13, pw = pp % 13;
        const _Float16* q = P2h + c * 676 + (2 * ph) * 26 + 2 * pw;
        h2 a = as_h2(*(const uint_t*)q);
        h2 d = as_h2(*(const uint_t*)(q + 26));
        float m = fmaxf(fmaxf((float)a[0], (float)a[1]),
                        fmaxf((float)d[0], (float)d[1]));
        write_rec(&smemA[s * SREC + pp * 60 + c * 12], m);
    }
    __syncthreads();

    // ---- Phase 4: conv2 5x5 (5c x 9feat -> 5o) -> h2buf ------------------
    if (tid < 162) {
        int s = (tid >= 81);
        int pp = tid - (s ? 81 : 0);
        const _Float16* sm = smemA + s * SREC;
        float* h2buf = (float*)(smemB + s * SB);
        int y = pp / 9, xx = pp % 9;
        float acc[5] = {0.f, 0.f, 0.f, 0.f, 0.f};
#pragma unroll 1
        for (int c = 0; c < 5; ++c) {
#pragma unroll 1
            for (int di = 0; di < 5; ++di) {
                const _Float16* base = &sm[((y + di) * 13 + xx) * 60 + c * 12];
                Rec r[5];
#pragma unroll
                for (int p = 0; p < 5; ++p) r[p] = load_rec(base + p * 60);
#pragma unroll
                for (int o = 0; o < 5; ++o) {
                    const h2* w = (const h2*)(w16 + W2_OFF + (o * 125 + c * 25 + di * 5) * 10);
                    float a = acc[o];
#pragma unroll
                    for (int dj = 0; dj < 5; ++dj)
#pragma unroll
                        for (int q = 0; q < 5; ++q)
                            a = fdot2f(r[dj].a[q], w[dj * 5 + q], a);
                    acc[o] = a;
                }
            }
        }
#pragma unroll
        for (int o = 0; o < 5; ++o) h2buf[o * 81 + pp] = acc[o];
    }
    __syncthreads();

    // ---- Phase 5: transform h2 -> t3 records -----------------------------
#pragma unroll 1
    for (int i = tid; i < 810; i += 256) {
        int s = (i >= 405);
        int r2 = i - (s ? 405 : 0);
        int o = r2 / 81, pp = r2 % 81;
        const float* h2buf = (const float*)(smemB + s * SB);
        write_rec(&smemA[s * SREC + pp * 60 + o * 12], h2buf[r2]);
    }
    __syncthreads();

    // ---- Phase 6: conv3 3x3 (5c x 9feat -> 2o) -> h3 (fp16) --------------
    if (tid < 98) {
        int s = (tid >= 49);
        int pp = tid - (s ? 49 : 0);
        const _Float16* sm = smemA + s * SREC;
        _Float16* h3h = smemB + s * SB;
        int y = pp / 7, xx = pp % 7;
        float acc[2] = {0.f, 0.f};
#pragma unroll 1
        for (int c = 0; c < 5; ++c) {
#pragma unroll 1
            for (int di = 0; di < 3; ++di) {
                const _Float16* base = &sm[((y + di) * 9 + xx) * 60 + c * 12];
                Rec r[3];
#pragma unroll
                for (int p = 0; p < 3; ++p) r[p] = load_rec(base + p * 60);
#pragma unroll
                for (int o = 0; o < 2; ++o) {
                    const h2* w = (const h2*)(w16 + W3_OFF + (o * 45 + c * 9 + di * 3) * 10);
                    float a = acc[o];
#pragma unroll
                    for (int dj = 0; dj < 3; ++dj)
#pragma unroll
                        for (int q = 0; q < 5; ++q)
                            a = fdot2f(r[dj].a[q], w[dj * 5 + q], a);
                    acc[o] = a;
                }
            }
        }
        h3h[pp]      = (_Float16)acc[0];
        h3h[49 + pp] = (_Float16)acc[1];
    }
    __syncthreads();

    // ---- Phase 7: FC [98] -> [200] via fp16 dot2 -------------------------
#pragma unroll 1
    for (int i = tid; i < 400; i += 256) {
        int s = (i >= 200);
        int o = i - (s ? 200 : 0);
        const h2* hh = (const h2*)(smemB + s * SB);   // 49 pairs, broadcast reads
        float acc = fcb[o];
        const uint_t* fw = fcw16 + o;
#pragma unroll
        for (int j2 = 0; j2 < 49; ++j2)
            acc = fdot2f(hh[j2], as_h2(fw[j2 * 200]), acc);
        if (b0 + s < B) out[(b0 + s) * 200 + o] = acc;
    }
}

extern "C" void kernel_launch(void* const* d_in, const int* in_sizes, int n_in,
                              void* d_out, int out_size, void* d_ws, size_t ws_size,
                              hipStream_t stream) {
    const float* x   = (const float*)d_in[0];
    const float* wb1 = (const float*)d_in[1];
    const float* ws1 = (const float*)d_in[2];
    const float* wb2 = (const float*)d_in[3];
    const float* ws2 = (const float*)d_in[4];
    const float* wb3 = (const float*)d_in[5];
    const float* ws3 = (const float*)d_in[6];
    const float* fcw = (const float*)d_in[7];
    const float* fcb = (const float*)d_in[8];
    float* out = (float*)d_out;

    _Float16* w16   = (_Float16*)d_ws;
    uint_t*   fcw16 = (uint_t*)((char*)d_ws + FCW16_BYTE_OFF);

    kan_prep<<<32, 256, 0, stream>>>(wb1, ws1, wb2, ws2, wb3, ws3, fcw, w16, fcw16);

    int B = in_sizes[0] / 784;  // 4096
    kan_fused<<<(B + 1) / 2, 256, 0, stream>>>(x, w16, fcw16, fcb, out, B);
}

// Round 6
// 258.609 us; speedup vs baseline: 1.1313x; 1.1313x over previous
//
#include <hip/hip_runtime.h>

// KAN conv feature extractor, fully fused: one workgroup (256 thr) per batch element.
// conv1 3x3 (1->5) + maxpool2 -> conv2 5x5 (5->5) -> conv3 3x3 (5->2) -> FC(98->200)
// Activations in LDS as fp16 "records" of 12 halves (24B): [silu, B0..B7, 0, p, p].
// Inner products via v_dot2_f32_f16 (fp32 accumulate).  Conv weights pre-packed to
// fp16 10-half records in d_ws (wave-uniform indices -> s_load).  FC weights packed
// as pair-transposed fp16.  B-spline basis evaluated analytically (4 cubics/span).
// R6 = R5 minus the divergent in-loop __syncthreads() (barrier divergence -> NaN).

typedef _Float16 h2 __attribute__((ext_vector_type(2)));
typedef unsigned int uint_t;

__device__ __forceinline__ h2 as_h2(uint_t u) { union { uint_t u; h2 h; } c; c.u = u; return c.h; }
__device__ __forceinline__ uint_t pk(float a, float b) {
    h2 v; v[0] = (_Float16)a; v[1] = (_Float16)b;
    union { h2 h; uint_t u; } c; c.h = v; return c.u;
}
__device__ __forceinline__ float fdot2f(h2 a, h2 b, float c) {
#if __has_builtin(__builtin_amdgcn_fdot2)
    return __builtin_amdgcn_fdot2(a, b, c, false);
#else
    return c + (float)a[0] * (float)b[0] + (float)a[1] * (float)b[1];
#endif
}

__device__ __forceinline__ float silu_f(float v) {
    return v / (1.0f + __expf(-v));
}

// Analytic cubic B-spline over uniform knots g_i = 0.4*i - 2.2 (i = 0..11).
// For x in span s, t = local coord: nonzero bases are j = s-3..s with the 4
// standard cubics.  Continuous across knots; outside [-2.2, 2.2) all zero.
// Writes fp16 record [silu, B0..B7, 0, 0, 0] (12 halves, 8B-aligned).
__device__ __forceinline__ void write_rec(_Float16* p, float v) {
    float u  = (v + 2.2f) * 2.5f;
    float fs = floorf(u);
    float t  = u - fs;
    float t2 = t * t, t3 = t2 * t;
    const float c6 = 1.0f / 6.0f;
    float q3 = t3 * c6;                                     // b[s]
    float q2 = (-3.f * t3 + 3.f * t2 + 3.f * t + 1.f) * c6; // b[s-1]
    float q1 = (3.f * t3 - 6.f * t2 + 4.f) * c6;            // b[s-2]
    float omt = 1.f - t;
    float q0 = omt * omt * omt * c6;                        // b[s-3]
    int si = (int)fs;
    bool valid = (u >= 0.0f) && (u < 11.0f);
    si = valid ? si : 1000;
    float bs[8];
#pragma unroll
    for (int j = 0; j < 8; ++j) {
        int d = si - j;
        bs[j] = (d == 0) ? q3 : (d == 1) ? q2 : (d == 2) ? q1 : (d == 3) ? q0 : 0.0f;
    }
    float sl = silu_f(v);
    uint2 w0, w1;
    w0.x = pk(sl, bs[0]);    w0.y = pk(bs[1], bs[2]);
    w1.x = pk(bs[3], bs[4]); w1.y = pk(bs[5], bs[6]);
    *(uint2*)(p)      = w0;
    *(uint2*)(p + 4)  = w1;
    *(uint_t*)(p + 8) = pk(bs[7], 0.0f);
}

struct Rec { h2 a[5]; };
__device__ __forceinline__ Rec load_rec(const _Float16* p) {
    uint2  u0 = *(const uint2*)(p);
    uint2  u1 = *(const uint2*)(p + 4);
    uint_t u2 = *(const uint_t*)(p + 8);
    Rec r;
    r.a[0] = as_h2(u0.x); r.a[1] = as_h2(u0.y);
    r.a[2] = as_h2(u1.x); r.a[3] = as_h2(u1.y);
    r.a[4] = as_h2(u2);
    return r;
}

// d_ws layout:
//   [0)       w16: fp16 conv weight records, 10 halves each:
//               W1 rec (c*9+t)             : 45 recs  @ half 0
//               W2 rec (o*125+c*25+di*5+dj): 625 recs @ half 450
//               W3 rec (o*45+c*9+di*3+dj)  : 90 recs  @ half 6700
//   [15360)   fcw16: uint [49][200], pair (fcw[o][2j], fcw[o][2j+1]) as h2
#define W2_OFF 450
#define W3_OFF 6700
#define FCW16_BYTE_OFF 15360

__global__ __launch_bounds__(256) void kan_prep(
    const float* __restrict__ wb1, const float* __restrict__ ws1,
    const float* __restrict__ wb2, const float* __restrict__ ws2,
    const float* __restrict__ wb3, const float* __restrict__ ws3,
    const float* __restrict__ fcw, _Float16* __restrict__ w16,
    uint_t* __restrict__ fcw16)
{
    int gtid = blockIdx.x * 256 + threadIdx.x;
    int gstr = gridDim.x * 256;
    for (int i = gtid; i < 760; i += gstr) {
        const float *wb, *ws; int r;
        if (i < 45)       { wb = wb1; ws = ws1; r = i; }
        else if (i < 670) { wb = wb2; ws = ws2; r = i - 45; }
        else              { wb = wb3; ws = ws3; r = i - 670; }
        _Float16* p = w16 + i * 10;
        p[0] = (_Float16)wb[r];
#pragma unroll
        for (int g = 0; g < 8; ++g) p[1 + g] = (_Float16)ws[r * 8 + g];
        p[9] = (_Float16)0.0f;
    }
    for (int i = gtid; i < 9800; i += gstr) {
        int j2 = i / 200, o = i % 200;
        fcw16[j2 * 200 + o] = pk(fcw[o * 98 + 2 * j2], fcw[o * 98 + 2 * j2 + 1]);
    }
}

// LDS: smemA (fp16 records, overlaid): t1 [784][12]=9408h | t2 [169][5][12]=10140h
//      | t3 [81][5][12]=4860h.  smemB (overlaid): P2h fp16 [5][676]=3380h |
//      h2buf f32 [405] | h3 fp16 [98].  Total 27.0 KB -> 6 WGs/CU.
#define SREC 10140
#define SB   3380

__global__ __launch_bounds__(256, 6) void kan_fused(
    const float* __restrict__ x,      // [B,1,28,28]
    const _Float16* __restrict__ w16, // packed conv weights (d_ws)
    const uint_t* __restrict__ fcw16, // [49][200] h2 pairs
    const float* __restrict__ fcb,    // [200]
    float* __restrict__ out)          // [B,200]
{
    __shared__ __align__(16) _Float16 smemA[SREC];
    __shared__ __align__(16) _Float16 smemB[SB];
    _Float16* P2h   = smemB;            // [c][676]
    float*    h2buf = (float*)smemB;    // [o*81+pp]
    _Float16* h3h   = smemB;            // [98]

    const int b   = blockIdx.x;
    const int tid = threadIdx.x;

    // ---- Phase 1: transform input pixels -> t1 records -------------------
#pragma unroll 1
    for (int i = tid; i < 784; i += 256)
        write_rec(&smemA[i * 12], x[b * 784 + i]);
    __syncthreads();

    // ---- Phase 2: conv1 3x3 at every sub-position (26x26), 5 out ch ------
    // lane = sub-position: stride-12 record reads, conflict-free; weights uniform.
#pragma unroll 1
    for (int s = tid; s < 676; s += 256) {
        int y = s / 26, xx = s % 26;
        Rec r[9];
#pragma unroll
        for (int t = 0; t < 9; ++t)
            r[t] = load_rec(&smemA[((y + t / 3) * 28 + xx + t % 3) * 12]);
        float acc[5] = {0.f, 0.f, 0.f, 0.f, 0.f};
#pragma unroll
        for (int t = 0; t < 9; ++t) {
#pragma unroll
            for (int c = 0; c < 5; ++c) {
                const h2* w = (const h2*)(w16 + (c * 9 + t) * 10);
                float a = acc[c];
#pragma unroll
                for (int q = 0; q < 5; ++q) a = fdot2f(r[t].a[q], w[q], a);
                acc[c] = a;
            }
        }
#pragma unroll
        for (int c = 0; c < 5; ++c) P2h[c * 676 + s] = (_Float16)acc[c];
    }
    __syncthreads();

    // ---- Phase 3: maxpool2 + transform -> t2 records ---------------------
#pragma unroll 1
    for (int i = tid; i < 845; i += 256) {
        int c = i / 169, pp = i % 169;
        int ph = pp / 13, pw = pp % 13;
        const _Float16* q = P2h + c * 676 + (2 * ph) * 26 + 2 * pw;
        h2 a = as_h2(*(const uint_t*)q);
        h2 d = as_h2(*(const uint_t*)(q + 26));
        float m = fmaxf(fmaxf((float)a[0], (float)a[1]),
                        fmaxf((float)d[0], (float)d[1]));
        write_rec(&smemA[pp * 60 + c * 12], m);
    }
    __syncthreads();

    // ---- Phase 4: conv2 5x5 (5c x 9feat -> 5o) -> h2buf ------------------
    if (tid < 81) {
        int y = tid / 9, xx = tid % 9;
        float acc[5] = {0.f, 0.f, 0.f, 0.f, 0.f};
#pragma unroll 1
        for (int c = 0; c < 5; ++c) {
#pragma unroll 1
            for (int di = 0; di < 5; ++di) {
                const _Float16* base = &smemA[((y + di) * 13 + xx) * 60 + c * 12];
                Rec r[5];
#pragma unroll
                for (int p = 0; p < 5; ++p) r[p] = load_rec(base + p * 60);
#pragma unroll
                for (int o = 0; o < 5; ++o) {
                    const h2* w = (const h2*)(w16 + W2_OFF + (o * 125 + c * 25 + di * 5) * 10);
                    float a = acc[o];
#pragma unroll
                    for (int dj = 0; dj < 5; ++dj)
#pragma unroll
                        for (int q = 0; q < 5; ++q)
                            a = fdot2f(r[dj].a[q], w[dj * 5 + q], a);
                    acc[o] = a;
                }
            }
        }
#pragma unroll
        for (int o = 0; o < 5; ++o) h2buf[o * 81 + tid] = acc[o];
    }
    __syncthreads();

    // ---- Phase 5: transform h2 -> t3 records -----------------------------
    // Reads h2buf (smemB), writes smemA: disjoint regions, no inner barrier
    // needed (h3h only overwrites h2buf in Phase 6, behind the next barrier).
#pragma unroll 1
    for (int i = tid; i < 405; i += 256) {
        int o = i / 81, pp = i % 81;
        write_rec(&smemA[pp * 60 + o * 12], h2buf[i]);
    }
    __syncthreads();

    // ---- Phase 6: conv3 3x3 (5c x 9feat -> 2o) -> h3 (fp16) --------------
    if (tid < 49) {
        int y = tid / 7, xx = tid % 7;
        float acc[2] = {0.f, 0.f};
#pragma unroll 1
        for (int c = 0; c < 5; ++c) {
#pragma unroll 1
            for (int di = 0; di < 3; ++di) {
                const _Float16* base = &smemA[((y + di) * 9 + xx) * 60 + c * 12];
                Rec r[3];
#pragma unroll
                for (int p = 0; p < 3; ++p) r[p] = load_rec(base + p * 60);
#pragma unroll
                for (int o = 0; o < 2; ++o) {
                    const h2* w = (const h2*)(w16 + W3_OFF + (o * 45 + c * 9 + di * 3) * 10);
                    float a = acc[o];
#pragma unroll
                    for (int dj = 0; dj < 3; ++dj)
#pragma unroll
                        for (int q = 0; q < 5; ++q)
                            a = fdot2f(r[dj].a[q], w[dj * 5 + q], a);
                    acc[o] = a;
                }
            }
        }
        h3h[tid]      = (_Float16)acc[0];
        h3h[49 + tid] = (_Float16)acc[1];
    }
    __syncthreads();

    // ---- Phase 7: FC [98] -> [200] via fp16 dot2 -------------------------
    if (tid < 200) {
        const h2* hh = (const h2*)h3h;   // 49 pairs, broadcast reads
        float acc = fcb[tid];
        const uint_t* fw = fcw16 + tid;
#pragma unroll
        for (int j2 = 0; j2 < 49; ++j2)
            acc = fdot2f(hh[j2], as_h2(fw[j2 * 200]), acc);
        out[b * 200 + tid] = acc;
    }
}

extern "C" void kernel_launch(void* const* d_in, const int* in_sizes, int n_in,
                              void* d_out, int out_size, void* d_ws, size_t ws_size,
                              hipStream_t stream) {
    const float* x   = (const float*)d_in[0];
    const float* wb1 = (const float*)d_in[1];
    const float* ws1 = (const float*)d_in[2];
    const float* wb2 = (const float*)d_in[3];
    const float* ws2 = (const float*)d_in[4];
    const float* wb3 = (const float*)d_in[5];
    const float* ws3 = (const float*)d_in[6];
    const float* fcw = (const float*)d_in[7];
    const float* fcb = (const float*)d_in[8];
    float* out = (float*)d_out;

    _Float16* w16   = (_Float16*)d_ws;
    uint_t*   fcw16 = (uint_t*)((char*)d_ws + FCW16_BYTE_OFF);

    kan_prep<<<32, 256, 0, stream>>>(wb1, ws1, wb2, ws2, wb3, ws3, fcw, w16, fcw16);

    int B = in_sizes[0] / 784;  // 4096
    kan_fused<<<B, 256, 0, stream>>>(x, w16, fcw16, fcb, out);
}